// Round 11
// baseline (405.667 us; speedup 1.0000x reference)
//
#include <hip/hip_runtime.h>
#include <math.h>

// Problem constants (from reference setup_inputs)
#define NB   8192   // batch
#define NC   3755   // chars
#define NR   214    // radicals
#define NS   13     // structure classes
#define NSC  30     // stroke-count bins
#define NST  6      // stroke types
#define NH   64     // hidden
#define KTOP 20     // top_k
#define RPB  4      // rows per block (one wave each)
#define NT   (RPB * 64)
#define NQT  15     // float4 slots per lane: ceil(938/64)
#define NBIN 1024   // histogram bins = top 10 bits of sort key
#define CAP  192    // candidate capacity per row (observed M ~ 85-130)

// monotonic float -> uint transform (ascending float => ascending unsigned key)
__device__ __forceinline__ unsigned sortkey(float x) {
    unsigned u = __float_as_uint(x);
    return (u & 0x80000000u) ? ~u : (u | 0x80000000u);
}

// __launch_bounds__(256, 8): 8 waves/EU -> allocator capped at 64 VGPR, so
// 8 blocks/CU (32 waves) become resident. The row is NOT kept in registers:
// streaming two-pass (reloads hit L2/L3; input fits in 256MB Infinity Cache).
__global__ __launch_bounds__(NT, 8) void reranker_kernel(
    const float* __restrict__ char_logits,     // (B, C)
    const float* __restrict__ radical_logits,  // (B, R)
    const float* __restrict__ structure,       // (B, S)
    const float* __restrict__ stroke_count,    // (B, NSC)
    const float* __restrict__ stroke_types,    // (B, NST)
    const int*   __restrict__ radical_mask,    // (C, R)
    const int*   __restrict__ structure_label, // (C,)
    const int*   __restrict__ stroke_count_label, // (C,)
    const float* __restrict__ stroke_type_sig, // (C, NST)
    const float* __restrict__ W1,              // (6, H)
    const float* __restrict__ b1,              // (H,)
    const float* __restrict__ W2,              // (H, 1)
    const float* __restrict__ b2,              // (1,)
    const float* __restrict__ rw,              // scalar
    float*       __restrict__ out)             // (B, C)
{
    const int tid  = threadIdx.x;
    const int lane = tid & 63;
    const int wave = tid >> 6;
    const int row  = blockIdx.x * RPB + wave;   // NB = 2048 * 4 exactly

    // LDS ~18.6 KB/block -> 8 blocks/CU fit (8*18.6 = 149 KB < 160)
    __shared__ unsigned s_hist32[RPB / 2][NBIN]; // 8 KB, 16-bit packed pairs
    __shared__ float s_candv[RPB][CAP];     // 3 KB
    __shared__ int   s_candi[RPB][CAP];     // 3 KB
    __shared__ float s_probs[RPB][216];     // sigmoid(radical row), padded
    __shared__ float s_topv[RPB][KTOP];
    __shared__ int   s_topi[RPB][KTOP];
    __shared__ float s_struct[RPB][NS];     // softmax(structure row)
    __shared__ float s_aux[RPB][8];         // [0..5] normalized stroke_types, [6] stroke_pred
    __shared__ int   s_cnt[RPB];
    __shared__ int   s_need[RPB];           // per-wave "needs full-histogram pass"

    const int      hw  = wave >> 1;          // histogram array index
    const unsigned hsh = (wave & 1) * 16;    // half-word shift for this wave

    const size_t rowOff = (size_t)row * NC;
    const float* __restrict__ rin  = char_logits + rowOff;
    float*       __restrict__ rout = out + rowOff;

    // alignment prolog: rows are 4B-aligned only (NC=3755)
    const int a     = (int)((4 - (rowOff & 3)) & 3);
    const int nq    = (NC - a) >> 2;            // 938 for all a in 0..3
    const int ntail = NC - a - 4 * nq;          // 3 - a

    int ext_idx = -1;
    if (lane < a)                           ext_idx = lane;
    else if (lane >= 8 && lane < 8 + ntail) ext_idx = a + 4 * nq + (lane - 8);

    // ---- zero histogram + counters ----
    for (int i = tid; i < (RPB / 2) * NBIN; i += NT)
        (&s_hist32[0][0])[i] = 0u;
    if (tid < RPB) s_cnt[tid] = 0;

    // ---- radical sigmoid probs (per-wave, lane-strided) ----
    float psum = 0.f;
#pragma unroll
    for (int i = 0; i < 4; ++i) {
        int r = lane + i * 64;
        if (r < NR) {
            float x = radical_logits[(size_t)row * NR + r];
            float pp = 1.f / (1.f + __expf(-x));
            s_probs[wave][r] = pp;
            psum += pp;
        }
    }

    // ---- per-row aux on lanes 0..2 of each wave (parallel across waves) ----
    if (lane == 0) {
        float sv[NS]; float m = -INFINITY;
#pragma unroll
        for (int i = 0; i < NS; ++i) { sv[i] = structure[(size_t)row * NS + i]; m = fmaxf(m, sv[i]); }
        float s = 0.f;
#pragma unroll
        for (int i = 0; i < NS; ++i) { sv[i] = __expf(sv[i] - m); s += sv[i]; }
        float inv = 1.f / s;
#pragma unroll
        for (int i = 0; i < NS; ++i) s_struct[wave][i] = sv[i] * inv;
    } else if (lane == 1) {
        float bv = -INFINITY; int bi = 0;
#pragma unroll
        for (int i = 0; i < NSC; ++i) {
            float x = stroke_count[(size_t)row * NSC + i];
            if (x > bv) { bv = x; bi = i; }
        }
        s_aux[wave][6] = (float)bi;
    } else if (lane == 2) {
        float t6[NST]; float ss = 0.f;
#pragma unroll
        for (int i = 0; i < NST; ++i) { t6[i] = stroke_types[(size_t)row * NST + i]; ss += t6[i] * t6[i]; }
        float inv = 1.f / fmaxf(sqrtf(ss), 1e-12f);
#pragma unroll
        for (int i = 0; i < NST; ++i) s_aux[wave][i] = t6[i] * inv;
    }
    __syncthreads();                                   // B1 (hist zero visible)

    // ---- PASS A: load + copy + max + filtered histogram (values transient) ----
    const unsigned floork1 = 0xBF800000u;              // sortkey(1.0f)
    float m0 = -INFINITY, m1 = -INFINITY, m2 = -INFINITY, m3 = -INFINITY;
    float ext = -INFINITY;
    if (ext_idx >= 0) {
        ext = rin[ext_idx]; rout[ext_idx] = ext;
        unsigned k = sortkey(ext);
        if (k >= floork1) atomicAdd(&s_hist32[hw][k >> 22], 1u << hsh);
    }
    for (int t = 0; t < NQT; ++t) {
        int q = lane + t * 64;
        if (q < nq) {
            float4 x = *reinterpret_cast<const float4*>(rin + a + 4 * q);
            *reinterpret_cast<float4*>(rout + a + 4 * q) = x;
            m0 = fmaxf(m0, x.x); m1 = fmaxf(m1, x.y);
            m2 = fmaxf(m2, x.z); m3 = fmaxf(m3, x.w);
            unsigned k0 = sortkey(x.x), k1 = sortkey(x.y);
            unsigned k2 = sortkey(x.z), k3 = sortkey(x.w);
            if (k0 >= floork1) atomicAdd(&s_hist32[hw][k0 >> 22], 1u << hsh);
            if (k1 >= floork1) atomicAdd(&s_hist32[hw][k1 >> 22], 1u << hsh);
            if (k2 >= floork1) atomicAdd(&s_hist32[hw][k2 >> 22], 1u << hsh);
            if (k3 >= floork1) atomicAdd(&s_hist32[hw][k3 >> 22], 1u << hsh);
        }
    }
    float lmax = fmaxf(fmaxf(m0, m1), fmaxf(fmaxf(m2, m3), ext));
#pragma unroll
    for (int off = 32; off > 0; off >>= 1) lmax = fmaxf(lmax, __shfl_xor(lmax, off));
    const float rowmax = lmax;
    __syncthreads();                                   // B2 (histogram complete)

    // ---- threshold scan (all lanes redundantly; wave-uniform result) ----
    int B0 = -1;
    {
        int bb = (int)(sortkey(rowmax) >> 22);
        int fb = (int)(floork1 >> 22);
        int cum = 0;
        while (bb >= fb) {
            cum += (int)((s_hist32[hw][bb] >> hsh) & 0xFFFFu);
            if (cum >= KTOP) break;
            --bb;
        }
        B0 = (cum >= KTOP) ? bb : -1;
    }
    const int need2 = (B0 < 0) ? 1 : 0;
    if (lane == 0) s_need[wave] = need2;
    __syncthreads();                                   // B3

    // block-uniform fallback (~never taken for N(0,1); reloads row, exact)
    const int any2 = s_need[0] | s_need[1] | s_need[2] | s_need[3];
    if (any2) {
        if (need2) {
#pragma unroll
            for (int i = 0; i < NBIN / 64; ++i) s_hist32[hw][lane + i * 64] = 0u;
        }
        __syncthreads();
        if (need2) {
            for (int t = 0; t < NQT; ++t) {
                int q = lane + t * 64;
                if (q < nq) {
                    float4 x = *reinterpret_cast<const float4*>(rin + a + 4 * q);
                    atomicAdd(&s_hist32[hw][sortkey(x.x) >> 22], 1u << hsh);
                    atomicAdd(&s_hist32[hw][sortkey(x.y) >> 22], 1u << hsh);
                    atomicAdd(&s_hist32[hw][sortkey(x.z) >> 22], 1u << hsh);
                    atomicAdd(&s_hist32[hw][sortkey(x.w) >> 22], 1u << hsh);
                }
            }
            if (ext_idx >= 0) atomicAdd(&s_hist32[hw][sortkey(ext) >> 22], 1u << hsh);
        }
        __syncthreads();
        if (need2) {
            int bb = (int)(sortkey(rowmax) >> 22);
            int cum = 0;
            while (bb >= 0) {
                cum += (int)((s_hist32[hw][bb] >> hsh) & 0xFFFFu);
                if (cum >= KTOP) break;
                --bb;
            }
            B0 = bb;                                   // guaranteed: all 3755 counted
        }
    }

    // ---- PASS B: reload (L2/L3-hot) -> exp-sum + candidate compaction ----
    float e0 = 0.f, e1 = 0.f, e2 = 0.f, e3 = 0.f;
    if (ext_idx >= 0) {
        e0 = __expf(ext - rowmax);
        if ((int)(sortkey(ext) >> 22) >= B0) {
            int pos = atomicAdd(&s_cnt[wave], 1);
            if (pos < CAP) { s_candv[wave][pos] = ext; s_candi[wave][pos] = ext_idx; }
        }
    }
    for (int t = 0; t < NQT; ++t) {
        int q = lane + t * 64;
        if (q < nq) {
            float4 x = *reinterpret_cast<const float4*>(rin + a + 4 * q);
            e0 += __expf(x.x - rowmax);
            e1 += __expf(x.y - rowmax);
            e2 += __expf(x.z - rowmax);
            e3 += __expf(x.w - rowmax);
            if ((int)(sortkey(x.x) >> 22) >= B0) {
                int pos = atomicAdd(&s_cnt[wave], 1);
                if (pos < CAP) { s_candv[wave][pos] = x.x; s_candi[wave][pos] = a + 4*q + 0; }
            }
            if ((int)(sortkey(x.y) >> 22) >= B0) {
                int pos = atomicAdd(&s_cnt[wave], 1);
                if (pos < CAP) { s_candv[wave][pos] = x.y; s_candi[wave][pos] = a + 4*q + 1; }
            }
            if ((int)(sortkey(x.z) >> 22) >= B0) {
                int pos = atomicAdd(&s_cnt[wave], 1);
                if (pos < CAP) { s_candv[wave][pos] = x.z; s_candi[wave][pos] = a + 4*q + 2; }
            }
            if ((int)(sortkey(x.w) >> 22) >= B0) {
                int pos = atomicAdd(&s_cnt[wave], 1);
                if (pos < CAP) { s_candv[wave][pos] = x.w; s_candi[wave][pos] = a + 4*q + 3; }
            }
        }
    }
    float le = (e0 + e1) + (e2 + e3);
#pragma unroll
    for (int off = 32; off > 0; off >>= 1) le += __shfl_xor(le, off);
    const float sumexp = le;
#pragma unroll
    for (int off = 32; off > 0; off >>= 1) psum += __shfl_xor(psum, off);
    const float total = psum;
    __syncthreads();                                   // B4 (compaction visible)

    int M = s_cnt[wave]; if (M > CAP) M = CAP;

    // ---- exact rank selection (val desc, idx asc — jax.lax.top_k ties) ----
    for (int c = lane; c < M; c += 64) {
        float cv = s_candv[wave][c]; int ci = s_candi[wave][c];
        int rank = 0;
        for (int j = 0; j < M; ++j) {
            float ov = s_candv[wave][j]; int oi = s_candi[wave][j];
            rank += (ov > cv || (ov == cv && oi < ci)) ? 1 : 0;
        }
        if (rank < KTOP) { s_topv[wave][rank] = cv; s_topi[wave][rank] = ci; }
    }
    __syncthreads();                                   // B5

    // ---- hoisted per-lane weights (small live set; wf[] is gone) ----
    const float b1v = b1[lane];
    float w1v[6];
#pragma unroll
    for (int j = 0; j < 6; ++j) w1v[j] = W1[j * NH + lane];
    const float w2v = W2[lane];
    const float b2v = b2[0];
    const float wrk = rw[0];
    const float spred = s_aux[wave][6];

    // ---- features + MLP fused, per candidate (whole wave cooperates) ----
    for (int k = 0; k < KTOP; ++k) {
        const int   ci = __builtin_amdgcn_readfirstlane(s_topi[wave][k]);  // SGPR-uniform
        const float tv = s_topv[wave][k];
        const int* __restrict__ mrow = radical_mask + (size_t)ci * NR;
        float det = 0.f, cnt = 0.f;
#pragma unroll
        for (int i = 0; i < 4; ++i) {
            int r = lane + i * 64;
            if (r < NR) {
                float m = (float)mrow[r];
                det += s_probs[wave][r] * m;
                cnt += m;
            }
        }
#pragma unroll
        for (int off = 32; off > 0; off >>= 1) {
            det += __shfl_xor(det, off);
            cnt += __shfl_xor(cnt, off);
        }
        // all lanes hold det/cnt; compute features redundantly (uniform scalar loads)
        float f1 = det / fmaxf(cnt, 1.f);
        float f2 = (total - det) / fmaxf(total, 1e-6f);
        float f3 = s_struct[wave][structure_label[ci]];
        float f4 = fabsf(spred - (float)stroke_count_label[ci]) * (1.f / 29.f);
        float sig[NST]; float ss = 0.f;
#pragma unroll
        for (int i = 0; i < NST; ++i) { sig[i] = stroke_type_sig[(size_t)ci * NST + i]; ss += sig[i] * sig[i]; }
        float nrm = sqrtf(ss);
        float has = (nrm > 1e-6f) ? 1.f : 0.f;
        float add = 1e-8f * (1.f - has);
        float ss2 = 0.f;
#pragma unroll
        for (int i = 0; i < NST; ++i) { sig[i] += add; ss2 += sig[i] * sig[i]; }
        float inv = 1.f / fmaxf(sqrtf(ss2), 1e-12f);
        float dot = 0.f;
#pragma unroll
        for (int i = 0; i < NST; ++i) dot += s_aux[wave][i] * sig[i] * inv;  // LDS broadcast, saves VGPRs
        float f5 = dot * has;
        float f6 = __expf(tv - rowmax) / sumexp;

        // MLP: lane = hidden unit (H == 64)
        float acc = b1v + f1 * w1v[0] + f2 * w1v[1] + f3 * w1v[2]
                        + f4 * w1v[3] + f5 * w1v[4] + f6 * w1v[5];
        float h = fmaxf(acc, 0.f);
        float part = h * w2v;
#pragma unroll
        for (int off = 32; off > 0; off >>= 1) part += __shfl_xor(part, off);
        if (lane == 0) rout[ci] = tv + wrk * (part + b2v);
    }
}

extern "C" void kernel_launch(void* const* d_in, const int* in_sizes, int n_in,
                              void* d_out, int out_size, void* d_ws, size_t ws_size,
                              hipStream_t stream) {
    (void)in_sizes; (void)n_in; (void)out_size; (void)d_ws; (void)ws_size;
    const float* char_logits        = (const float*)d_in[0];
    const float* radical_logits     = (const float*)d_in[1];
    const float* structure          = (const float*)d_in[2];
    const float* stroke_count      = (const float*)d_in[3];
    const float* stroke_types       = (const float*)d_in[4];
    const int*   radical_mask       = (const int*)d_in[5];
    const int*   structure_label    = (const int*)d_in[6];
    const int*   stroke_count_label = (const int*)d_in[7];
    const float* stroke_type_sig    = (const float*)d_in[8];
    const float* W1                 = (const float*)d_in[9];
    const float* b1                 = (const float*)d_in[10];
    const float* W2                 = (const float*)d_in[11];
    const float* b2                 = (const float*)d_in[12];
    const float* rw                 = (const float*)d_in[13];
    float* out = (float*)d_out;

    reranker_kernel<<<NB / RPB, NT, 0, stream>>>(
        char_logits, radical_logits, structure, stroke_count, stroke_types,
        radical_mask, structure_label, stroke_count_label, stroke_type_sig,
        W1, b1, W2, b2, rw, out);
}

// Round 12
// 391.018 us; speedup vs baseline: 1.0375x; 1.0375x over previous
//
#include <hip/hip_runtime.h>
#include <math.h>

// Problem constants (from reference setup_inputs)
#define NB   8192   // batch
#define NC   3755   // chars
#define NR   214    // radicals
#define NS   13     // structure classes
#define NSC  30     // stroke-count bins
#define NST  6      // stroke types
#define NH   64     // hidden
#define KTOP 20     // top_k
#define RPB  4      // rows per block in select kernel (one wave each)
#define NT   (RPB * 64)
#define NQT  15     // float4 slots per lane: ceil(938/64)
#define NBIN 1024   // histogram bins = top 10 bits of sort key
#define CAP  192    // candidate capacity per row (observed M ~ 85-130)

// monotonic float -> uint transform (ascending float => ascending unsigned key)
__device__ __forceinline__ unsigned sortkey(float x) {
    unsigned u = __float_as_uint(x);
    return (u & 0x80000000u) ? ~u : (u | 0x80000000u);
}
__device__ __forceinline__ float inv_sortkey(unsigned k) {
    unsigned u = (k & 0x80000000u) ? (k ^ 0x80000000u) : ~k;
    return __uint_as_float(u);
}

// ============================ KERNEL A: select ============================
// wave-per-row streaming two-pass: copy + rowmax + filtered histogram; scan;
// reload: exp-sum + compaction (packed u64); rank-select -> workspace.
__global__ __launch_bounds__(NT, 8) void select_kernel(
    const float* __restrict__ char_logits,
    float*       __restrict__ out,
    float*       __restrict__ ws_topv,   // (NB, KTOP)
    int*         __restrict__ ws_topi,   // (NB, KTOP)
    float*       __restrict__ ws_stat)   // (NB, 2): rowmax, sumexp
{
    const int tid  = threadIdx.x;
    const int lane = tid & 63;
    const int wave = tid >> 6;
    const int row  = blockIdx.x * RPB + wave;

    __shared__ unsigned           s_hist32[RPB / 2][NBIN]; // 8 KB, 16-bit packed
    __shared__ unsigned long long s_cand[RPB][CAP];        // 6 KB packed key|~idx
    __shared__ int s_cnt[RPB];
    __shared__ int s_need[RPB];

    const int      hw  = wave >> 1;
    const unsigned hsh = (wave & 1) * 16;

    const size_t rowOff = (size_t)row * NC;
    const float* __restrict__ rin  = char_logits + rowOff;
    float*       __restrict__ rout = out + rowOff;

    const int a     = (int)((4 - (rowOff & 3)) & 3);
    const int nq    = (NC - a) >> 2;
    const int ntail = NC - a - 4 * nq;

    int ext_idx = -1;
    if (lane < a)                           ext_idx = lane;
    else if (lane >= 8 && lane < 8 + ntail) ext_idx = a + 4 * nq + (lane - 8);

    for (int i = tid; i < (RPB / 2) * NBIN; i += NT)
        (&s_hist32[0][0])[i] = 0u;
    if (tid < RPB) s_cnt[tid] = 0;
    __syncthreads();                                   // B1

    // ---- PASS A: load + copy + max + tight-filtered histogram ----
    // filter at x >= 2.0: E[count] = 85 +- 9 for N(0,1) rows; needing the
    // 20th value below 2.0 is a ~7-sigma event, and the exact fallback exists.
    const unsigned floork1 = 0xC0000000u;              // sortkey(2.0f)
    float m0 = -INFINITY, m1 = -INFINITY, m2 = -INFINITY, m3 = -INFINITY;
    float ext = -INFINITY;
    if (ext_idx >= 0) {
        ext = rin[ext_idx]; rout[ext_idx] = ext;
        unsigned k = sortkey(ext);
        if (k >= floork1) atomicAdd(&s_hist32[hw][k >> 22], 1u << hsh);
    }
    for (int t = 0; t < NQT; ++t) {
        int q = lane + t * 64;
        if (q < nq) {
            float4 x = *reinterpret_cast<const float4*>(rin + a + 4 * q);
            *reinterpret_cast<float4*>(rout + a + 4 * q) = x;
            m0 = fmaxf(m0, x.x); m1 = fmaxf(m1, x.y);
            m2 = fmaxf(m2, x.z); m3 = fmaxf(m3, x.w);
            unsigned k0 = sortkey(x.x), k1 = sortkey(x.y);
            unsigned k2 = sortkey(x.z), k3 = sortkey(x.w);
            if (k0 >= floork1) atomicAdd(&s_hist32[hw][k0 >> 22], 1u << hsh);
            if (k1 >= floork1) atomicAdd(&s_hist32[hw][k1 >> 22], 1u << hsh);
            if (k2 >= floork1) atomicAdd(&s_hist32[hw][k2 >> 22], 1u << hsh);
            if (k3 >= floork1) atomicAdd(&s_hist32[hw][k3 >> 22], 1u << hsh);
        }
    }
    float lmax = fmaxf(fmaxf(m0, m1), fmaxf(fmaxf(m2, m3), ext));
#pragma unroll
    for (int off = 32; off > 0; off >>= 1) lmax = fmaxf(lmax, __shfl_xor(lmax, off));
    const float rowmax = lmax;
    __syncthreads();                                   // B2

    // ---- threshold scan (all lanes redundantly; wave-uniform result) ----
    int B0 = -1;
    {
        int bb = (int)(sortkey(rowmax) >> 22);
        int fb = (int)(floork1 >> 22);
        int cum = 0;
        while (bb >= fb) {
            cum += (int)((s_hist32[hw][bb] >> hsh) & 0xFFFFu);
            if (cum >= KTOP) break;
            --bb;
        }
        B0 = (cum >= KTOP) ? bb : -1;
    }
    const int need2 = (B0 < 0) ? 1 : 0;
    if (lane == 0) s_need[wave] = need2;
    __syncthreads();                                   // B3

    // block-uniform exact fallback (~never taken for N(0,1))
    const int any2 = s_need[0] | s_need[1] | s_need[2] | s_need[3];
    if (any2) {
        if (need2) {
#pragma unroll
            for (int i = 0; i < NBIN / 64; ++i) s_hist32[hw][lane + i * 64] = 0u;
        }
        __syncthreads();
        if (need2) {
            for (int t = 0; t < NQT; ++t) {
                int q = lane + t * 64;
                if (q < nq) {
                    float4 x = *reinterpret_cast<const float4*>(rin + a + 4 * q);
                    atomicAdd(&s_hist32[hw][sortkey(x.x) >> 22], 1u << hsh);
                    atomicAdd(&s_hist32[hw][sortkey(x.y) >> 22], 1u << hsh);
                    atomicAdd(&s_hist32[hw][sortkey(x.z) >> 22], 1u << hsh);
                    atomicAdd(&s_hist32[hw][sortkey(x.w) >> 22], 1u << hsh);
                }
            }
            if (ext_idx >= 0) atomicAdd(&s_hist32[hw][sortkey(ext) >> 22], 1u << hsh);
        }
        __syncthreads();
        if (need2) {
            int bb = (int)(sortkey(rowmax) >> 22);
            int cum = 0;
            while (bb >= 0) {
                cum += (int)((s_hist32[hw][bb] >> hsh) & 0xFFFFu);
                if (cum >= KTOP) break;
                --bb;
            }
            B0 = bb;
        }
    }

    // ---- PASS B: reload -> exp-sum + packed candidate compaction ----
    float e0 = 0.f, e1 = 0.f, e2 = 0.f, e3 = 0.f;
    if (ext_idx >= 0) {
        e0 = __expf(ext - rowmax);
        unsigned k = sortkey(ext);
        if ((int)(k >> 22) >= B0) {
            int pos = atomicAdd(&s_cnt[wave], 1);
            if (pos < CAP)
                s_cand[wave][pos] = ((unsigned long long)k << 32) | (0xFFFFFFFFu - (unsigned)ext_idx);
        }
    }
    for (int t = 0; t < NQT; ++t) {
        int q = lane + t * 64;
        if (q < nq) {
            float4 x = *reinterpret_cast<const float4*>(rin + a + 4 * q);
            e0 += __expf(x.x - rowmax);
            e1 += __expf(x.y - rowmax);
            e2 += __expf(x.z - rowmax);
            e3 += __expf(x.w - rowmax);
            unsigned kk[4] = { sortkey(x.x), sortkey(x.y), sortkey(x.z), sortkey(x.w) };
#pragma unroll
            for (int j = 0; j < 4; ++j) {
                if ((int)(kk[j] >> 22) >= B0) {
                    int pos = atomicAdd(&s_cnt[wave], 1);
                    if (pos < CAP)
                        s_cand[wave][pos] = ((unsigned long long)kk[j] << 32)
                                          | (0xFFFFFFFFu - (unsigned)(a + 4*q + j));
                }
            }
        }
    }
    float le = (e0 + e1) + (e2 + e3);
#pragma unroll
    for (int off = 32; off > 0; off >>= 1) le += __shfl_xor(le, off);
    __syncthreads();                                   // B4

    int M = s_cnt[wave]; if (M > CAP) M = CAP;

    // ---- rank selection: packed compare (val desc, idx asc) -> workspace ----
    for (int c = lane; c < M; c += 64) {
        unsigned long long pc = s_cand[wave][c];
        int rank = 0;
        for (int j = 0; j < M; ++j) rank += (s_cand[wave][j] > pc) ? 1 : 0;
        if (rank < KTOP) {
            ws_topv[(size_t)row * KTOP + rank] = inv_sortkey((unsigned)(pc >> 32));
            ws_topi[(size_t)row * KTOP + rank] = (int)(0xFFFFFFFFu - (unsigned)(pc & 0xFFFFFFFFu));
        }
    }
    if (lane == 0) {
        ws_stat[2 * row + 0] = rowmax;
        ws_stat[2 * row + 1] = le;
    }
}

// ============================ KERNEL B: rerank ============================
// block-per-row: sigmoid/aux prologue, then 4 waves x 5 candidates each
// compute features + MLP + scatter.
__global__ __launch_bounds__(256, 8) void rerank_kernel(
    const float* __restrict__ radical_logits,
    const float* __restrict__ structure,
    const float* __restrict__ stroke_count,
    const float* __restrict__ stroke_types,
    const int*   __restrict__ radical_mask,
    const int*   __restrict__ structure_label,
    const int*   __restrict__ stroke_count_label,
    const float* __restrict__ stroke_type_sig,
    const float* __restrict__ W1,
    const float* __restrict__ b1,
    const float* __restrict__ W2,
    const float* __restrict__ b2,
    const float* __restrict__ rw,
    const float* __restrict__ ws_topv,
    const int*   __restrict__ ws_topi,
    const float* __restrict__ ws_stat,
    float*       __restrict__ out)
{
    const int row  = blockIdx.x;
    const int tid  = threadIdx.x;
    const int lane = tid & 63;
    const int wave = tid >> 6;

    __shared__ float s_probs[216];
    __shared__ float s_struct[NS];
    __shared__ float s_aux[8];       // [0..5] normalized stroke_types, [6] stroke_pred
    __shared__ float s_topv[KTOP];
    __shared__ int   s_topi[KTOP];
    __shared__ float s_stat2[2];

    if (tid < NR)
        s_probs[tid] = 1.f / (1.f + __expf(-radical_logits[(size_t)row * NR + tid]));
    if (tid < KTOP) {
        s_topv[tid] = ws_topv[(size_t)row * KTOP + tid];
        s_topi[tid] = ws_topi[(size_t)row * KTOP + tid];
    }
    if (tid == 216) {
        float sv[NS]; float m = -INFINITY;
#pragma unroll
        for (int i = 0; i < NS; ++i) { sv[i] = structure[(size_t)row * NS + i]; m = fmaxf(m, sv[i]); }
        float s = 0.f;
#pragma unroll
        for (int i = 0; i < NS; ++i) { sv[i] = __expf(sv[i] - m); s += sv[i]; }
        float inv = 1.f / s;
#pragma unroll
        for (int i = 0; i < NS; ++i) s_struct[i] = sv[i] * inv;
    } else if (tid == 217) {
        float bv = -INFINITY; int bi = 0;
#pragma unroll
        for (int i = 0; i < NSC; ++i) {
            float x = stroke_count[(size_t)row * NSC + i];
            if (x > bv) { bv = x; bi = i; }
        }
        s_aux[6] = (float)bi;
    } else if (tid == 218) {
        float t6[NST]; float ss = 0.f;
#pragma unroll
        for (int i = 0; i < NST; ++i) { t6[i] = stroke_types[(size_t)row * NST + i]; ss += t6[i] * t6[i]; }
        float inv = 1.f / fmaxf(sqrtf(ss), 1e-12f);
#pragma unroll
        for (int i = 0; i < NST; ++i) s_aux[i] = t6[i] * inv;
    } else if (tid == 219) {
        s_stat2[0] = ws_stat[2 * row + 0];
        s_stat2[1] = ws_stat[2 * row + 1];
    }
    __syncthreads();

    // per-wave: total radical prob (lane-strided LDS + butterfly)
    float psum = 0.f;
#pragma unroll
    for (int i = 0; i < 4; ++i) {
        int r = lane + i * 64;
        if (r < NR) psum += s_probs[r];
    }
#pragma unroll
    for (int off = 32; off > 0; off >>= 1) psum += __shfl_xor(psum, off);
    const float total = psum;

    const float rowmax = s_stat2[0];
    const float sumexp = s_stat2[1];
    const float b1v = b1[lane];
    float w1v[6];
#pragma unroll
    for (int j = 0; j < 6; ++j) w1v[j] = W1[j * NH + lane];
    const float w2v = W2[lane];
    const float b2v = b2[0];
    const float wrk = rw[0];
    const float spred = s_aux[6];

    // ---- 5 candidates per wave ----
#pragma unroll
    for (int j = 0; j < KTOP / 4; ++j) {
        const int   k  = wave * (KTOP / 4) + j;
        const int   ci = __builtin_amdgcn_readfirstlane(s_topi[k]);
        const float tv = s_topv[k];
        const int* __restrict__ mrow = radical_mask + (size_t)ci * NR;
        float det = 0.f, cnt = 0.f;
#pragma unroll
        for (int i = 0; i < 4; ++i) {
            int r = lane + i * 64;
            if (r < NR) {
                float m = (float)mrow[r];
                det += s_probs[r] * m;
                cnt += m;
            }
        }
#pragma unroll
        for (int off = 32; off > 0; off >>= 1) {
            det += __shfl_xor(det, off);
            cnt += __shfl_xor(cnt, off);
        }
        float f1 = det / fmaxf(cnt, 1.f);
        float f2 = (total - det) / fmaxf(total, 1e-6f);
        float f3 = s_struct[structure_label[ci]];
        float f4 = fabsf(spred - (float)stroke_count_label[ci]) * (1.f / 29.f);
        float sig[NST]; float ss = 0.f;
#pragma unroll
        for (int i = 0; i < NST; ++i) { sig[i] = stroke_type_sig[(size_t)ci * NST + i]; ss += sig[i] * sig[i]; }
        float nrm = sqrtf(ss);
        float has = (nrm > 1e-6f) ? 1.f : 0.f;
        float add = 1e-8f * (1.f - has);
        float ss2 = 0.f;
#pragma unroll
        for (int i = 0; i < NST; ++i) { sig[i] += add; ss2 += sig[i] * sig[i]; }
        float inv = 1.f / fmaxf(sqrtf(ss2), 1e-12f);
        float dot = 0.f;
#pragma unroll
        for (int i = 0; i < NST; ++i) dot += s_aux[i] * sig[i] * inv;
        float f5 = dot * has;
        float f6 = __expf(tv - rowmax) / sumexp;

        float acc = b1v + f1 * w1v[0] + f2 * w1v[1] + f3 * w1v[2]
                        + f4 * w1v[3] + f5 * w1v[4] + f6 * w1v[5];
        float h = fmaxf(acc, 0.f);
        float part = h * w2v;
#pragma unroll
        for (int off = 32; off > 0; off >>= 1) part += __shfl_xor(part, off);
        if (lane == 0) out[(size_t)row * NC + ci] = tv + wrk * (part + b2v);
    }
}

extern "C" void kernel_launch(void* const* d_in, const int* in_sizes, int n_in,
                              void* d_out, int out_size, void* d_ws, size_t ws_size,
                              hipStream_t stream) {
    (void)in_sizes; (void)n_in; (void)out_size; (void)ws_size;
    const float* char_logits        = (const float*)d_in[0];
    const float* radical_logits     = (const float*)d_in[1];
    const float* structure          = (const float*)d_in[2];
    const float* stroke_count       = (const float*)d_in[3];
    const float* stroke_types       = (const float*)d_in[4];
    const int*   radical_mask       = (const int*)d_in[5];
    const int*   structure_label    = (const int*)d_in[6];
    const int*   stroke_count_label = (const int*)d_in[7];
    const float* stroke_type_sig    = (const float*)d_in[8];
    const float* W1                 = (const float*)d_in[9];
    const float* b1                 = (const float*)d_in[10];
    const float* W2                 = (const float*)d_in[11];
    const float* b2                 = (const float*)d_in[12];
    const float* rw                 = (const float*)d_in[13];
    float* out = (float*)d_out;

    // workspace layout: topv (NB*KTOP f32) | topi (NB*KTOP i32) | stat (NB*2 f32)
    float* ws_topv = (float*)d_ws;                       // 655,360 B
    int*   ws_topi = (int*)(ws_topv + (size_t)NB * KTOP); // 655,360 B
    float* ws_stat = (float*)(ws_topi + (size_t)NB * KTOP); // 65,536 B  (total ~1.38 MB)

    select_kernel<<<NB / RPB, NT, 0, stream>>>(char_logits, out, ws_topv, ws_topi, ws_stat);
    rerank_kernel<<<NB, 256, 0, stream>>>(
        radical_logits, structure, stroke_count, stroke_types,
        radical_mask, structure_label, stroke_count_label, stroke_type_sig,
        W1, b1, W2, b2, rw, ws_topv, ws_topi, ws_stat, out);
}

// Round 13
// 343.670 us; speedup vs baseline: 1.1804x; 1.1378x over previous
//
#include <hip/hip_runtime.h>
#include <math.h>

// Problem constants (from reference setup_inputs)
#define NB   8192   // batch
#define NC   3755   // chars
#define NR   214    // radicals
#define NS   13     // structure classes
#define NSC  30     // stroke-count bins
#define NST  6      // stroke types
#define NH   64     // hidden
#define KTOP 20     // top_k
#define RPB  4      // rows per block in select kernel (one wave each)
#define NT   (RPB * 64)
#define NQT  15     // float4 slots per lane: ceil(938/64)
#define NBIN 1024   // histogram bins (fallback only)
#define CAP  192    // candidate capacity per row (E[M]=85, sd 9 for N(0,1))

// monotonic float -> uint transform (ascending float => ascending unsigned key)
__device__ __forceinline__ unsigned sortkey(float x) {
    unsigned u = __float_as_uint(x);
    return (u & 0x80000000u) ? ~u : (u | 0x80000000u);
}
__device__ __forceinline__ float inv_sortkey(unsigned k) {
    unsigned u = (k & 0x80000000u) ? (k ^ 0x80000000u) : ~k;
    return __uint_as_float(u);
}

// ============================ KERNEL A: select ============================
// SINGLE-PASS: load float4 -> copy to out; accumulate sum(exp(x)) directly
// (no max subtraction; safe for |rowmax|<=60, guarded); running max; inline
// static-filter compaction (x >= 2.0 -> packed u64 in LDS). Histogram runs
// only in the ~never-taken exact fallback.
__global__ __launch_bounds__(NT, 8) void select_kernel(
    const float* __restrict__ char_logits,
    float*       __restrict__ out,
    float*       __restrict__ ws_topv,   // (NB, KTOP)
    int*         __restrict__ ws_topi,   // (NB, KTOP)
    float*       __restrict__ ws_stat)   // (NB, 2): rowmax, sumexp
{
    const int tid  = threadIdx.x;
    const int lane = tid & 63;
    const int wave = tid >> 6;
    const int row  = blockIdx.x * RPB + wave;

    __shared__ unsigned           s_hist32[RPB / 2][NBIN]; // 8 KB, fallback only
    __shared__ unsigned long long s_cand[RPB][CAP];        // 6 KB packed key|~idx
    __shared__ int s_cnt[RPB];
    __shared__ int s_need[RPB];

    const int      hw  = wave >> 1;
    const unsigned hsh = (wave & 1) * 16;

    const size_t rowOff = (size_t)row * NC;
    const float* __restrict__ rin  = char_logits + rowOff;
    float*       __restrict__ rout = out + rowOff;

    const int a     = (int)((4 - (rowOff & 3)) & 3);
    const int nq    = (NC - a) >> 2;
    const int ntail = NC - a - 4 * nq;

    int ext_idx = -1;
    if (lane < a)                           ext_idx = lane;
    else if (lane >= 8 && lane < 8 + ntail) ext_idx = a + 4 * nq + (lane - 8);

    if (tid < RPB) s_cnt[tid] = 0;
    __syncthreads();                                   // B1 (cnt zero visible)

    // ---- single fused pass ----
    const unsigned FLOORK = 0xC0000000u;               // sortkey(2.0f)
    float m0 = -INFINITY, m1 = -INFINITY, m2 = -INFINITY, m3 = -INFINITY;
    float e0 = 0.f, e1 = 0.f, e2 = 0.f, e3 = 0.f;
    float ext = -INFINITY;
    if (ext_idx >= 0) {
        ext = rin[ext_idx]; rout[ext_idx] = ext;
        e0 += __expf(ext);                              // exp(-inf)=0 if absent
        m0 = fmaxf(m0, ext);
        unsigned k = sortkey(ext);
        if (k >= FLOORK) {
            int pos = atomicAdd(&s_cnt[wave], 1);
            if (pos < CAP)
                s_cand[wave][pos] = ((unsigned long long)k << 32) | (0xFFFFFFFFu - (unsigned)ext_idx);
        }
    }
    for (int t = 0; t < NQT; ++t) {
        int q = lane + t * 64;
        if (q < nq) {
            float4 x = *reinterpret_cast<const float4*>(rin + a + 4 * q);
            *reinterpret_cast<float4*>(rout + a + 4 * q) = x;
            e0 += __expf(x.x); e1 += __expf(x.y);
            e2 += __expf(x.z); e3 += __expf(x.w);
            m0 = fmaxf(m0, x.x); m1 = fmaxf(m1, x.y);
            m2 = fmaxf(m2, x.z); m3 = fmaxf(m3, x.w);
            unsigned kk[4] = { sortkey(x.x), sortkey(x.y), sortkey(x.z), sortkey(x.w) };
#pragma unroll
            for (int j = 0; j < 4; ++j) {
                if (kk[j] >= FLOORK) {
                    int pos = atomicAdd(&s_cnt[wave], 1);
                    if (pos < CAP)
                        s_cand[wave][pos] = ((unsigned long long)kk[j] << 32)
                                          | (0xFFFFFFFFu - (unsigned)(a + 4*q + j));
                }
            }
        }
    }
    float lmax = fmaxf(fmaxf(m0, m1), fmaxf(m2, m3));
#pragma unroll
    for (int off = 32; off > 0; off >>= 1) lmax = fmaxf(lmax, __shfl_xor(lmax, off));
    const float rowmax = lmax;
    float S = (e0 + e1) + (e2 + e3);
#pragma unroll
    for (int off = 32; off > 0; off >>= 1) S += __shfl_xor(S, off);

    int M = s_cnt[wave];     // own-wave LDS ops are ordered; safe without barrier
    const bool ok = (M >= KTOP) && (M <= CAP) && (fabsf(rowmax) <= 60.f);
    float sumexp = S * __expf(-rowmax);   // == sum(exp(x-rowmax)) up to rounding
    if (lane == 0) s_need[wave] = ok ? 0 : 1;
    __syncthreads();                                   // B2
    const int any = s_need[0] | s_need[1] | s_need[2] | s_need[3];

    if (any) {   // exact fallback (~never for N(0,1)); block-uniform barriers
        const bool bad = !ok;
        for (int i = tid; i < (RPB / 2) * NBIN; i += NT)
            (&s_hist32[0][0])[i] = 0u;
        __syncthreads();
        if (bad) {
            if (ext_idx >= 0) atomicAdd(&s_hist32[hw][sortkey(ext) >> 22], 1u << hsh);
            for (int t = 0; t < NQT; ++t) {
                int q = lane + t * 64;
                if (q < nq) {
                    float4 x = *reinterpret_cast<const float4*>(rin + a + 4 * q);
                    atomicAdd(&s_hist32[hw][sortkey(x.x) >> 22], 1u << hsh);
                    atomicAdd(&s_hist32[hw][sortkey(x.y) >> 22], 1u << hsh);
                    atomicAdd(&s_hist32[hw][sortkey(x.z) >> 22], 1u << hsh);
                    atomicAdd(&s_hist32[hw][sortkey(x.w) >> 22], 1u << hsh);
                }
            }
        }
        __syncthreads();
        int B0 = 0;
        if (bad) {
            int bb = (int)(sortkey(rowmax) >> 22), cum = 0;
            while (bb >= 0) {
                cum += (int)((s_hist32[hw][bb] >> hsh) & 0xFFFFu);
                if (cum >= KTOP) break;
                --bb;
            }
            B0 = (bb < 0) ? 0 : bb;
            if (lane == 0) s_cnt[wave] = 0;
        }
        __syncthreads();
        if (bad) {
            float f0 = 0.f, f1 = 0.f, f2 = 0.f, f3 = 0.f;
            if (ext_idx >= 0) {
                f0 += __expf(ext - rowmax);
                unsigned k = sortkey(ext);
                if ((int)(k >> 22) >= B0) {
                    int pos = atomicAdd(&s_cnt[wave], 1);
                    if (pos < CAP)
                        s_cand[wave][pos] = ((unsigned long long)k << 32) | (0xFFFFFFFFu - (unsigned)ext_idx);
                }
            }
            for (int t = 0; t < NQT; ++t) {
                int q = lane + t * 64;
                if (q < nq) {
                    float4 x = *reinterpret_cast<const float4*>(rin + a + 4 * q);
                    f0 += __expf(x.x - rowmax); f1 += __expf(x.y - rowmax);
                    f2 += __expf(x.z - rowmax); f3 += __expf(x.w - rowmax);
                    unsigned kk[4] = { sortkey(x.x), sortkey(x.y), sortkey(x.z), sortkey(x.w) };
#pragma unroll
                    for (int j = 0; j < 4; ++j) {
                        if ((int)(kk[j] >> 22) >= B0) {
                            int pos = atomicAdd(&s_cnt[wave], 1);
                            if (pos < CAP)
                                s_cand[wave][pos] = ((unsigned long long)kk[j] << 32)
                                                  | (0xFFFFFFFFu - (unsigned)(a + 4*q + j));
                        }
                    }
                }
            }
            float ls = (f0 + f1) + (f2 + f3);
#pragma unroll
            for (int off = 32; off > 0; off >>= 1) ls += __shfl_xor(ls, off);
            sumexp = ls;
            M = s_cnt[wave]; if (M > CAP) M = CAP;
        }
    }

    // ---- rank selection: packed compare (val desc, idx asc) -> workspace ----
    for (int c = lane; c < M; c += 64) {
        unsigned long long pc = s_cand[wave][c];
        int rank = 0;
        for (int j = 0; j < M; ++j) rank += (s_cand[wave][j] > pc) ? 1 : 0;
        if (rank < KTOP) {
            ws_topv[(size_t)row * KTOP + rank] = inv_sortkey((unsigned)(pc >> 32));
            ws_topi[(size_t)row * KTOP + rank] = (int)(0xFFFFFFFFu - (unsigned)(pc & 0xFFFFFFFFu));
        }
    }
    if (lane == 0) {
        ws_stat[2 * row + 0] = rowmax;
        ws_stat[2 * row + 1] = sumexp;
    }
}

// ============================ KERNEL B: rerank ============================
// UNCHANGED from round 12 (clean attribution; its counters will appear in
// the top-5 once select drops below it).
__global__ __launch_bounds__(256, 8) void rerank_kernel(
    const float* __restrict__ radical_logits,
    const float* __restrict__ structure,
    const float* __restrict__ stroke_count,
    const float* __restrict__ stroke_types,
    const int*   __restrict__ radical_mask,
    const int*   __restrict__ structure_label,
    const int*   __restrict__ stroke_count_label,
    const float* __restrict__ stroke_type_sig,
    const float* __restrict__ W1,
    const float* __restrict__ b1,
    const float* __restrict__ W2,
    const float* __restrict__ b2,
    const float* __restrict__ rw,
    const float* __restrict__ ws_topv,
    const int*   __restrict__ ws_topi,
    const float* __restrict__ ws_stat,
    float*       __restrict__ out)
{
    const int row  = blockIdx.x;
    const int tid  = threadIdx.x;
    const int lane = tid & 63;
    const int wave = tid >> 6;

    __shared__ float s_probs[216];
    __shared__ float s_struct[NS];
    __shared__ float s_aux[8];       // [0..5] normalized stroke_types, [6] stroke_pred
    __shared__ float s_topv[KTOP];
    __shared__ int   s_topi[KTOP];
    __shared__ float s_stat2[2];

    if (tid < NR)
        s_probs[tid] = 1.f / (1.f + __expf(-radical_logits[(size_t)row * NR + tid]));
    if (tid < KTOP) {
        s_topv[tid] = ws_topv[(size_t)row * KTOP + tid];
        s_topi[tid] = ws_topi[(size_t)row * KTOP + tid];
    }
    if (tid == 216) {
        float sv[NS]; float m = -INFINITY;
#pragma unroll
        for (int i = 0; i < NS; ++i) { sv[i] = structure[(size_t)row * NS + i]; m = fmaxf(m, sv[i]); }
        float s = 0.f;
#pragma unroll
        for (int i = 0; i < NS; ++i) { sv[i] = __expf(sv[i] - m); s += sv[i]; }
        float inv = 1.f / s;
#pragma unroll
        for (int i = 0; i < NS; ++i) s_struct[i] = sv[i] * inv;
    } else if (tid == 217) {
        float bv = -INFINITY; int bi = 0;
#pragma unroll
        for (int i = 0; i < NSC; ++i) {
            float x = stroke_count[(size_t)row * NSC + i];
            if (x > bv) { bv = x; bi = i; }
        }
        s_aux[6] = (float)bi;
    } else if (tid == 218) {
        float t6[NST]; float ss = 0.f;
#pragma unroll
        for (int i = 0; i < NST; ++i) { t6[i] = stroke_types[(size_t)row * NST + i]; ss += t6[i] * t6[i]; }
        float inv = 1.f / fmaxf(sqrtf(ss), 1e-12f);
#pragma unroll
        for (int i = 0; i < NST; ++i) s_aux[i] = t6[i] * inv;
    } else if (tid == 219) {
        s_stat2[0] = ws_stat[2 * row + 0];
        s_stat2[1] = ws_stat[2 * row + 1];
    }
    __syncthreads();

    // per-wave: total radical prob (lane-strided LDS + butterfly)
    float psum = 0.f;
#pragma unroll
    for (int i = 0; i < 4; ++i) {
        int r = lane + i * 64;
        if (r < NR) psum += s_probs[r];
    }
#pragma unroll
    for (int off = 32; off > 0; off >>= 1) psum += __shfl_xor(psum, off);
    const float total = psum;

    const float rowmax = s_stat2[0];
    const float sumexp = s_stat2[1];
    const float b1v = b1[lane];
    float w1v[6];
#pragma unroll
    for (int j = 0; j < 6; ++j) w1v[j] = W1[j * NH + lane];
    const float w2v = W2[lane];
    const float b2v = b2[0];
    const float wrk = rw[0];
    const float spred = s_aux[6];

    // ---- 5 candidates per wave ----
#pragma unroll
    for (int j = 0; j < KTOP / 4; ++j) {
        const int   k  = wave * (KTOP / 4) + j;
        const int   ci = __builtin_amdgcn_readfirstlane(s_topi[k]);
        const float tv = s_topv[k];
        const int* __restrict__ mrow = radical_mask + (size_t)ci * NR;
        float det = 0.f, cnt = 0.f;
#pragma unroll
        for (int i = 0; i < 4; ++i) {
            int r = lane + i * 64;
            if (r < NR) {
                float m = (float)mrow[r];
                det += s_probs[r] * m;
                cnt += m;
            }
        }
#pragma unroll
        for (int off = 32; off > 0; off >>= 1) {
            det += __shfl_xor(det, off);
            cnt += __shfl_xor(cnt, off);
        }
        float f1 = det / fmaxf(cnt, 1.f);
        float f2 = (total - det) / fmaxf(total, 1e-6f);
        float f3 = s_struct[structure_label[ci]];
        float f4 = fabsf(spred - (float)stroke_count_label[ci]) * (1.f / 29.f);
        float sig[NST]; float ss = 0.f;
#pragma unroll
        for (int i = 0; i < NST; ++i) { sig[i] = stroke_type_sig[(size_t)ci * NST + i]; ss += sig[i] * sig[i]; }
        float nrm = sqrtf(ss);
        float has = (nrm > 1e-6f) ? 1.f : 0.f;
        float add = 1e-8f * (1.f - has);
        float ss2 = 0.f;
#pragma unroll
        for (int i = 0; i < NST; ++i) { sig[i] += add; ss2 += sig[i] * sig[i]; }
        float inv = 1.f / fmaxf(sqrtf(ss2), 1e-12f);
        float dot = 0.f;
#pragma unroll
        for (int i = 0; i < NST; ++i) dot += s_aux[i] * sig[i] * inv;
        float f5 = dot * has;
        float f6 = __expf(tv - rowmax) / sumexp;

        float acc = b1v + f1 * w1v[0] + f2 * w1v[1] + f3 * w1v[2]
                        + f4 * w1v[3] + f5 * w1v[4] + f6 * w1v[5];
        float h = fmaxf(acc, 0.f);
        float part = h * w2v;
#pragma unroll
        for (int off = 32; off > 0; off >>= 1) part += __shfl_xor(part, off);
        if (lane == 0) out[(size_t)row * NC + ci] = tv + wrk * (part + b2v);
    }
}

extern "C" void kernel_launch(void* const* d_in, const int* in_sizes, int n_in,
                              void* d_out, int out_size, void* d_ws, size_t ws_size,
                              hipStream_t stream) {
    (void)in_sizes; (void)n_in; (void)out_size; (void)ws_size;
    const float* char_logits        = (const float*)d_in[0];
    const float* radical_logits     = (const float*)d_in[1];
    const float* structure          = (const float*)d_in[2];
    const float* stroke_count       = (const float*)d_in[3];
    const float* stroke_types       = (const float*)d_in[4];
    const int*   radical_mask       = (const int*)d_in[5];
    const int*   structure_label    = (const int*)d_in[6];
    const int*   stroke_count_label = (const int*)d_in[7];
    const float* stroke_type_sig    = (const float*)d_in[8];
    const float* W1                 = (const float*)d_in[9];
    const float* b1                 = (const float*)d_in[10];
    const float* W2                 = (const float*)d_in[11];
    const float* b2                 = (const float*)d_in[12];
    const float* rw                 = (const float*)d_in[13];
    float* out = (float*)d_out;

    // workspace layout: topv (NB*KTOP f32) | topi (NB*KTOP i32) | stat (NB*2 f32)
    float* ws_topv = (float*)d_ws;
    int*   ws_topi = (int*)(ws_topv + (size_t)NB * KTOP);
    float* ws_stat = (float*)(ws_topi + (size_t)NB * KTOP);

    select_kernel<<<NB / RPB, NT, 0, stream>>>(char_logits, out, ws_topv, ws_topi, ws_stat);
    rerank_kernel<<<NB, 256, 0, stream>>>(
        radical_logits, structure, stroke_count, stroke_types,
        radical_mask, structure_label, stroke_count_label, stroke_type_sig,
        W1, b1, W2, b2, rw, ws_topv, ws_topi, ws_stat, out);
}